// Round 15
// baseline (225.047 us; speedup 1.0000x reference)
//
#include <hip/hip_runtime.h>
#include <stdint.h>

// DynamicSparseLinearAttention on MI355X.
// N=4, L=8192, H=8, D=V=128. Layout [n][l][h][d], row stride H*D = 1024 floats.
//
// Lessons: (R4) atomics write through L2 -> never. (R5) small grids starve the
// chip. (R6) strided per-lane loads w/o staging thrash L2. (R8) scalar LDS
// transpose reads -> stage transposed+bf16-packed, b128 frag reads. (R9-R14)
// short-stage/barrier/compute x16 loops are pinned at ~100us regardless of
// load width, occupancy, buffering, barrier flavor: 5 nulls. The session's
// fast kernels (attn_out 4.4TB/s) share ONE shape: long burst (>=16 loads/thr
// in flight) -> one barrier -> barrier-free compute. R14 = attn-shaped phase 1.
//
// 3 launches:
//  kv_burst: grid (CH=32,8,4)=1024 blocks x 256 thr (4 waves = 2 wr(d64) x
//            2 wc(v64)). Per 128-s tile: ONE 32xfloat4/thread burst (512B in
//            flight/thread), R13's verified pack+shfl_xor(32) transpose staging
//            into [d][s2^swz] LDS (SPN=68), one barrier, then barrier-free
//            4 ksteps x 16 MFMA (+ ones-MFMA Ksum on wc==0). 2 tiles/block,
//            acc persists, 3 barriers/tile-pair. bf16 partials, write-once.
//  kv_merge: sum CH bf16 partials in fp32 -> kvb bf16 [nh][v][d] + ksumg.
//  attn_out: Q staged to LDS bf16 (row*17 padded), score during staging
//            (fp32 + shfl_xor), B-frags direct from L2-hot kvb. One barrier.

#define LSEQ 8192
#define NHD  1024   // H*D
#define SPN  68     // LDS dwords per d-row: 64 s-pair slots + 4 pad

typedef __attribute__((ext_vector_type(4))) float f32x4;
typedef __attribute__((ext_vector_type(8))) short bf16x8;
typedef unsigned short ushort_t;

static __device__ __forceinline__ unsigned short f2bf(float x) {
  union { float f; uint32_t u; } v; v.f = x;
  uint32_t r = v.u + 0x7FFFu + ((v.u >> 16) & 1u);  // RNE
  return (unsigned short)(r >> 16);
}
static __device__ __forceinline__ uint32_t pack_bf(float a, float b) {
  return (uint32_t)f2bf(a) | ((uint32_t)f2bf(b) << 16);
}
static __device__ __forceinline__ float featmap(float x) {
  // elu(x)+1 = x+1 (x>0) else exp(x)
  return x > 0.f ? x + 1.f : __expf(x);
}

// LDS-only barrier (ds ops drained; global loads stay in flight).
#define BAR_LGKM() asm volatile("s_waitcnt lgkmcnt(0)\n\ts_barrier" ::: "memory")

// ---------------- Phase 1: burst-staged KV GEMM ----------------
// Grid (CH, 8 h, 4 n), 256 thr = 4 waves; wave w: wr=w>>1 (d-half), wc=w&1
// (v-half). Wave's staging band: s-rows [32w, 32w+32) of the 128-s tile.
// Lane a: q=a&31 (d-quad 4q..4q+3), av=a>>5. Rows rb=32w+4*sub (sub 0..7):
// lane loads rows rb+av, rb+av+2 (float4). shfl_xor(32) pair-exchange builds
// s-pair words; av=0 writes slot 16w+2sub, av=1 slot 16w+2sub+1 (R13-verified).
__global__ __launch_bounds__(256, 2) void kv_burst(const float* __restrict__ keys,
                                                   const float* __restrict__ values,
                                                   ushort_t* __restrict__ kvpb,
                                                   float* __restrict__ kspart) {
  __shared__ uint32_t kls[128 * SPN];
  __shared__ uint32_t vls[128 * SPN];
  const int tid = threadIdx.x;
  const int chunk = blockIdx.x, CH = gridDim.x;
  const int h = blockIdx.y, n = blockIdx.z, nh = n * 8 + h;
  const int lane = tid & 63, w = tid >> 6;
  const int wr = w >> 1, wc = w & 1;
  const int lr = lane & 15, lg = lane >> 4;
  const int sPer = LSEQ / CH;          // 256 at CH=32
  const int tiles = sPer / 128;        // 2 at CH=32

  const size_t gb = ((size_t)n * LSEQ + (size_t)chunk * sPer) * NHD + h * 128;
  const float* gk = keys + gb;
  const float* gv = values + gb;

  const int av = lane >> 5;
  const int q  = lane & 31;
  const int swzq = 4 * ((q >> 1) & 3);     // = 4*((d>>3)&3) for d=4q..4q+3

  f32x4 acc[4][4] = {};
  f32x4 ak[4] = {};
  bf16x8 ones;
  { uint32_t* u = (uint32_t*)&ones; u[0] = u[1] = u[2] = u[3] = 0x3F803F80u; }

  float4 kr4[16], vr4[16];

#define ISSUE(TB)                                                          \
  do {                                                                     \
    _Pragma("unroll") for (int sub = 0; sub < 8; ++sub)                    \
      _Pragma("unroll") for (int i = 0; i < 2; ++i) {                      \
        size_t off = (size_t)((TB) * 128 + 32 * w + 4 * sub + av + 2 * i) * NHD + 4 * q; \
        kr4[sub * 2 + i] = *(const float4*)(gk + off);                     \
        vr4[sub * 2 + i] = *(const float4*)(gv + off);                     \
      }                                                                    \
  } while (0)

#define STAGE()                                                            \
  do {                                                                     \
    _Pragma("unroll") for (int sub = 0; sub < 8; ++sub) {                  \
      const int base0 = (4 * q) * SPN + ((16 * w + 2 * sub + av) ^ swzq);  \
      uint2 u0, u1, p0, p1, lo, hi;                                        \
      u0.x = pack_bf(featmap(kr4[2 * sub].x), featmap(kr4[2 * sub].y));    \
      u0.y = pack_bf(featmap(kr4[2 * sub].z), featmap(kr4[2 * sub].w));    \
      u1.x = pack_bf(featmap(kr4[2 * sub + 1].x), featmap(kr4[2 * sub + 1].y)); \
      u1.y = pack_bf(featmap(kr4[2 * sub + 1].z), featmap(kr4[2 * sub + 1].w)); \
      p0.x = __shfl_xor((int)u0.x, 32); p0.y = __shfl_xor((int)u0.y, 32);  \
      p1.x = __shfl_xor((int)u1.x, 32); p1.y = __shfl_xor((int)u1.y, 32);  \
      lo.x = av ? p1.x : u0.x;  lo.y = av ? p1.y : u0.y;                   \
      hi.x = av ? u1.x : p0.x;  hi.y = av ? u1.y : p0.y;                   \
      kls[base0]           = (lo.x & 0xFFFFu) | (hi.x << 16);              \
      kls[base0 + SPN]     = (lo.x >> 16) | (hi.x & 0xFFFF0000u);          \
      kls[base0 + 2 * SPN] = (lo.y & 0xFFFFu) | (hi.y << 16);              \
      kls[base0 + 3 * SPN] = (lo.y >> 16) | (hi.y & 0xFFFF0000u);          \
      u0.x = pack_bf(vr4[2 * sub].x, vr4[2 * sub].y);                      \
      u0.y = pack_bf(vr4[2 * sub].z, vr4[2 * sub].w);                      \
      u1.x = pack_bf(vr4[2 * sub + 1].x, vr4[2 * sub + 1].y);              \
      u1.y = pack_bf(vr4[2 * sub + 1].z, vr4[2 * sub + 1].w);              \
      p0.x = __shfl_xor((int)u0.x, 32); p0.y = __shfl_xor((int)u0.y, 32);  \
      p1.x = __shfl_xor((int)u1.x, 32); p1.y = __shfl_xor((int)u1.y, 32);  \
      lo.x = av ? p1.x : u0.x;  lo.y = av ? p1.y : u0.y;                   \
      hi.x = av ? u1.x : p0.x;  hi.y = av ? u1.y : p0.y;                   \
      vls[base0]           = (lo.x & 0xFFFFu) | (hi.x << 16);              \
      vls[base0 + SPN]     = (lo.x >> 16) | (hi.x & 0xFFFF0000u);          \
      vls[base0 + 2 * SPN] = (lo.y & 0xFFFFu) | (hi.y << 16);              \
      vls[base0 + 3 * SPN] = (lo.y >> 16) | (hi.y & 0xFFFF0000u);          \
    }                                                                      \
  } while (0)

  ISSUE(0);
  for (int tb = 0; tb < tiles; ++tb) {
    STAGE();
    BAR_LGKM();                      // staged words visible to all waves
    if (tb + 1 < tiles) ISSUE(tb + 1);   // next tile's burst flies under MFMA
    // ---- barrier-free MFMA phase: 4 ksteps x (16 MFMA + ksum) ----
#pragma unroll
    for (int ks = 0; ks < 4; ++ks) {
      bf16x8 af[4], bfr[4];
#pragma unroll
      for (int fr = 0; fr < 4; ++fr) {
        int d = wr * 64 + fr * 16 + lr;
        af[fr] = *(const bf16x8*)&kls[d * SPN + ((16 * ks + 4 * lg) ^ (4 * ((d >> 3) & 3)))];
      }
#pragma unroll
      for (int fc = 0; fc < 4; ++fc) {
        int v = wc * 64 + fc * 16 + lr;
        bfr[fc] = *(const bf16x8*)&vls[v * SPN + ((16 * ks + 4 * lg) ^ (4 * ((v >> 3) & 3)))];
      }
#pragma unroll
      for (int fr = 0; fr < 4; ++fr)
#pragma unroll
        for (int fc = 0; fc < 4; ++fc)
          acc[fr][fc] = __builtin_amdgcn_mfma_f32_16x16x32_bf16(af[fr], bfr[fc], acc[fr][fc], 0, 0, 0);
      if (wc == 0) {
#pragma unroll
        for (int fr = 0; fr < 4; ++fr)
          ak[fr] = __builtin_amdgcn_mfma_f32_16x16x32_bf16(af[fr], ones, ak[fr], 0, 0, 0);
      }
    }
    BAR_LGKM();                      // all reads done before next stage
  }
#undef ISSUE
#undef STAGE

  // C/D: col=lane&15, row=(lane>>4)*4+j. bf16 partial, write-once, no atomics.
  ushort_t* dst = kvpb + ((size_t)chunk * 32 + nh) * 16384;
#pragma unroll
  for (int fr = 0; fr < 4; ++fr)
#pragma unroll
    for (int fc = 0; fc < 4; ++fc) {
      int d0 = wr * 64 + fr * 16 + lg * 4;
      int v  = wc * 64 + fc * 16 + lr;
      *(uint2*)(dst + (size_t)v * 128 + d0) =
          make_uint2(pack_bf(acc[fr][fc][0], acc[fr][fc][1]),
                     pack_bf(acc[fr][fc][2], acc[fr][fc][3]));
    }
  if (wc == 0 && lr == 0) {
    float* ks = kspart + ((size_t)chunk * 32 + nh) * 128;
#pragma unroll
    for (int fr = 0; fr < 4; ++fr)
      *(float4*)(ks + wr * 64 + fr * 16 + lg * 4) =
          make_float4(ak[fr][0], ak[fr][1], ak[fr][2], ak[fr][3]);
  }
}

// ---------------- Phase 1c: merge bf16 partials ----------------
__global__ __launch_bounds__(256) void kv_merge(const ushort_t* __restrict__ kvpb,
                                                const float* __restrict__ kspart,
                                                ushort_t* __restrict__ kvb,
                                                float* __restrict__ ksumg,
                                                int CH) {
  const int nh = blockIdx.x, q = blockIdx.y, tid = threadIdx.x;
  const size_t off = (size_t)nh * 16384 + q * 4096;
#pragma unroll
  for (int i = 0; i < 4; ++i) {
    size_t idx = off + (size_t)(i * 256 + tid) * 4;
    f32x4 s = {};
    for (int c = 0; c < CH; ++c) {
      uint2 u = *(const uint2*)(kvpb + (size_t)c * 524288 + idx);
      s[0] += __uint_as_float(u.x << 16);
      s[1] += __uint_as_float(u.x & 0xFFFF0000u);
      s[2] += __uint_as_float(u.y << 16);
      s[3] += __uint_as_float(u.y & 0xFFFF0000u);
    }
    *(uint2*)(kvb + idx) = make_uint2(pack_bf(s[0], s[1]), pack_bf(s[2], s[3]));
  }
  if (q == 0 && tid < 128) {
    float s = 0.f;
    for (int c = 0; c < CH; ++c) s += kspart[((size_t)c * 32 + nh) * 128 + tid];
    ksumg[nh * 128 + tid] = s;
  }
}

// ---------------- Phase 2: LDS-staged Q + direct-global B ----------------
__global__ __launch_bounds__(256, 4) void attn_out(const float* __restrict__ q,
                                                   const ushort_t* __restrict__ kvb,
                                                   const float* __restrict__ ksumg,
                                                   const float* __restrict__ thrp,
                                                   float* __restrict__ out) {
  __shared__ __align__(16) uint32_t As[128 * 17 * 4];  // 34.8KB
  __shared__ float zrow[128];

  const int tid = threadIdx.x;
  const int mc = blockIdx.x, nh = blockIdx.y;
  const int n = nh >> 3, h = nh & 7;
  const size_t qoff = ((size_t)(n * LSEQ + mc * 128)) * NHD + h * 128;
  const float thr = thrp[0];

  const int c4 = tid & 31;
  const float4 kk = *(const float4*)(ksumg + nh * 128 + c4 * 4);

  // ---- stage Qf -> As (bf16) + fp32 score on the fly ----
#pragma unroll
  for (int it = 0; it < 16; ++it) {
    int rr = it * 8 + (tid >> 5);
    float4 qv = *(const float4*)(q + qoff + (size_t)rr * NHD + c4 * 4);
    float f0 = featmap(qv.x), f1 = featmap(qv.y), f2 = featmap(qv.z), f3 = featmap(qv.w);
    uint32_t* dst = &As[(rr * 17 + (c4 >> 1)) * 4 + (c4 & 1) * 2];
    dst[0] = pack_bf(f0, f1);
    dst[1] = pack_bf(f2, f3);
    float p = f0 * kk.x + f1 * kk.y + f2 * kk.z + f3 * kk.w;
    p += __shfl_xor(p, 1);  p += __shfl_xor(p, 2);  p += __shfl_xor(p, 4);
    p += __shfl_xor(p, 8);  p += __shfl_xor(p, 16);
    if (c4 == 0) {
      float sp = p > thr ? p : 0.f;
      zrow[rr] = 1.f / (sp + 1e-6f);
    }
  }
  __syncthreads();

  // ---- MFMA: A from LDS, B direct from kvb (L2-hot 32KB) ----
  const int lane = tid & 63;
  const int w = tid >> 6;
  const int lr = lane & 15, lg = lane >> 4;
  const ushort_t* kvp = kvb + (size_t)nh * 16384;   // [v][d] bf16

  f32x4 acc0[8] = {};
  f32x4 acc1[8] = {};
#pragma unroll
  for (int ks = 0; ks < 4; ++ks) {
    const int c8 = ks * 4 + lg;
    const int dof = ks * 32 + lg * 8;
    const int r0 = w * 32 + lr;
    bf16x8 a0 = *(const bf16x8*)&As[(r0 * 17 + c8) * 4];
    bf16x8 a1 = *(const bf16x8*)&As[((r0 + 16) * 17 + c8) * 4];
#pragma unroll
    for (int ct = 0; ct < 8; ++ct) {
      bf16x8 bb = *(const bf16x8*)(kvp + (size_t)((ct * 16 + lr) * 128) + dof);
      acc0[ct] = __builtin_amdgcn_mfma_f32_16x16x32_bf16(a0, bb, acc0[ct], 0, 0, 0);
      acc1[ct] = __builtin_amdgcn_mfma_f32_16x16x32_bf16(a1, bb, acc1[ct], 0, 0, 0);
    }
  }

  float z0[4], z1[4];
#pragma unroll
  for (int j = 0; j < 4; ++j) {
    z0[j] = zrow[w * 32 + lg * 4 + j];
    z1[j] = zrow[w * 32 + 16 + lg * 4 + j];
  }
  float* op = out + qoff;
#pragma unroll
  for (int ct = 0; ct < 8; ++ct)
#pragma unroll
    for (int jj = 0; jj < 4; ++jj) {
      int row = w * 32 + lg * 4 + jj;   // C/D: col=lane&15, row=(lane>>4)*4+jj
      op[(size_t)row * NHD + ct * 16 + lr]        = acc0[ct][jj] * z0[jj];
      op[(size_t)(row + 16) * NHD + ct * 16 + lr] = acc1[ct][jj] * z1[jj];
    }
}

extern "C" void kernel_launch(void* const* d_in, const int* in_sizes, int n_in,
                              void* d_out, int out_size, void* d_ws, size_t ws_size,
                              hipStream_t stream) {
  const float* queries   = (const float*)d_in[0];
  const float* keys      = (const float*)d_in[1];
  const float* values    = (const float*)d_in[2];
  const float* threshold = (const float*)d_in[3];
  float* out = (float*)d_out;

  // ws: kvpb CH*1MB bf16 | kspart CH*16KB | kvb 1MB | ksumg 16KB (CH=32 ~34MB)
  int CH = 32;
  while (CH > 2 &&
         (size_t)CH * (524288 * 2 + 32 * 128 * 4) + (size_t)32 * 16384 * 2 + 32 * 128 * 4 > ws_size)
    CH >>= 1;
  ushort_t* kvpb = (ushort_t*)d_ws;
  float* kspart  = (float*)(kvpb + (size_t)CH * 524288);
  ushort_t* kvb  = (ushort_t*)(kspart + (size_t)CH * 32 * 128);
  float* ksumg   = (float*)(kvb + (size_t)32 * 16384);

  kv_burst<<<dim3(CH, 8, 4), 256, 0, stream>>>(keys, values, kvpb, kspart);
  kv_merge<<<dim3(32, 4), 256, 0, stream>>>(kvpb, kspart, kvb, ksumg, CH);
  attn_out<<<dim3(64, 32), 256, 0, stream>>>(queries, kvb, ksumg, threshold, out);
}

// Round 16
// 174.107 us; speedup vs baseline: 1.2926x; 1.2926x over previous
//
#include <hip/hip_runtime.h>
#include <stdint.h>

// DynamicSparseLinearAttention on MI355X.
// N=4, L=8192, H=8, D=V=128. Layout [n][l][h][d], row stride H*D = 1024 floats.
//
// Lessons: (R4) atomics write through L2 -> never. (R5) small grids starve the
// chip. (R6) strided per-lane loads w/o staging thrash L2. (R8) scalar LDS
// transpose reads -> stage transposed+bf16-packed, b128 frag reads. (R9-R15)
// phase-1 is pinned ~100us across 6 structural mechanisms (load width,
// occupancy, conflicts, prefetch depth, barrier flavor, burst shape) with all
// pipes <15% busy. Untested correlation: slow kernels all read K+V as a pair
// at EXACTLY 2^27 B offset (R5: 2^26) -> suspected HBM channel-hash aliasing.
// R15 = revert to best config (R10, 172.5us) + stagger V rows by 16 so
// same-wave K/V addresses differ by 128MB +/- 64KB. Zero-cost A/B test.
//
// 3 launches:
//  kv_direct: fused retile+GEMM. Grid (CH=16,8,4)=512 blocks x 512 thr (8 waves
//             = 2 wr(d64) x 4 wc(v32)). Pipeline: regs P/Q hold steps t+2/t+3;
//             LDS buffers A/B alternate; one __syncthreads per substep. LDS
//             [d][s2^f(d)], SP=20. V staged by wave w at rows 4*((w+4)&7)+j
//             (channel stagger; LDS slots follow the row -> layout identical).
//             fp32 partials, write-once, no atomics. Ksum via ones-MFMA.
//  kv_merge:  sum CH partials -> kvb bf16 [nh][v][d] + ksumg.
//  attn_out:  Q staged to LDS bf16 (row*17 padded chunks), score during staging
//             (fp32 + shfl_xor), B-frags direct from L2-hot kvb. One barrier.

#define LSEQ 8192
#define NHD  1024   // H*D
#define SP   20     // LDS dwords per d-row: 16 s-pair slots + 4 pad

typedef __attribute__((ext_vector_type(4))) float f32x4;
typedef __attribute__((ext_vector_type(8))) short bf16x8;
typedef unsigned short ushort_t;

static __device__ __forceinline__ unsigned short f2bf(float x) {
  union { float f; uint32_t u; } v; v.f = x;
  uint32_t r = v.u + 0x7FFFu + ((v.u >> 16) & 1u);  // RNE
  return (unsigned short)(r >> 16);
}
static __device__ __forceinline__ uint32_t pack_bf(float a, float b) {
  return (uint32_t)f2bf(a) | ((uint32_t)f2bf(b) << 16);
}
static __device__ __forceinline__ float featmap(float x) {
  // elu(x)+1 = x+1 (x>0) else exp(x)
  return x > 0.f ? x + 1.f : __expf(x);
}

// ---------------- Phase 1: fused retile + KV GEMM, 2-deep pipeline ----------
// Grid (CH, 8 h, 4 n), 512 thr = 8 waves = 2 wr(d64) x 4 wc(v32).
__global__ __launch_bounds__(512, 4) void kv_direct(const float* __restrict__ keys,
                                                    const float* __restrict__ values,
                                                    float* __restrict__ kvp,
                                                    float* __restrict__ kspart) {
  __shared__ uint32_t klsA[128 * SP];
  __shared__ uint32_t vlsA[128 * SP];
  __shared__ uint32_t klsB[128 * SP];
  __shared__ uint32_t vlsB[128 * SP];
  const int tid = threadIdx.x;
  const int chunk = blockIdx.x, CH = gridDim.x;
  const int h = blockIdx.y, n = blockIdx.z, nh = n * 8 + h;
  const int lane = tid & 63, w = tid >> 6;
  const int wr = w >> 2, wc = w & 3;
  const int lr = lane & 15, lg = lane >> 4;
  const int sPer = LSEQ / CH;        // 512 at CH=16
  const int steps = sPer / 32;       // 16 at CH=16 (always even)

  const size_t gb = ((size_t)n * LSEQ + (size_t)chunk * sPer) * NHD + h * 128;
  const float* gk = keys + gb;
  const float* gv = values + gb;

  // staging role: wave w owns K rows 4w..4w+3; V rows 4wv..4wv+3 (wv = w+4 mod
  // 8, channel stagger: +/-64KB address skew between a wave's K and V loads).
  // Lane a owns d-pair (2a, 2a+1). LDS slots follow the actual row staged.
  const int a = lane;
  const int wv = (w + 4) & 7;
  const int fsw = 4 * ((a >> 2) & 3);          // = 4*((d>>3)&3) for d=2a,2a+1
  const int kslot = (2 * w) ^ fsw;
  const int vslot = (2 * wv) ^ fsw;
  const int kb0 = (2 * a) * SP + kslot;
  const int kb1 = (2 * a + 1) * SP + kslot;
  const int vb0 = (2 * a) * SP + vslot;
  const int vb1 = (2 * a + 1) * SP + vslot;

  f32x4 acc[4][2] = {};
  f32x4 ak[4] = {};
  bf16x8 ones;
  { uint32_t* u = (uint32_t*)&ones; u[0] = u[1] = u[2] = u[3] = 0x3F803F80u; }

#define ISSUE(KR, VR, T)                                           \
  do {                                                             \
    _Pragma("unroll") for (int j = 0; j < 4; ++j) {                \
      KR[j] = *(const float2*)(gk + (size_t)((T) * 32 + 4 * w + j) * NHD + 2 * a);  \
      VR[j] = *(const float2*)(gv + (size_t)((T) * 32 + 4 * wv + j) * NHD + 2 * a); \
    }                                                              \
  } while (0)

#define STAGE(KLS, VLS, KR, VR)                                 \
  do {                                                          \
    uint2 kd0, kd1, vd0, vd1;                                   \
    kd0.x = pack_bf(featmap(KR[0].x), featmap(KR[1].x));        \
    kd0.y = pack_bf(featmap(KR[2].x), featmap(KR[3].x));        \
    kd1.x = pack_bf(featmap(KR[0].y), featmap(KR[1].y));        \
    kd1.y = pack_bf(featmap(KR[2].y), featmap(KR[3].y));        \
    vd0.x = pack_bf(VR[0].x, VR[1].x);                          \
    vd0.y = pack_bf(VR[2].x, VR[3].x);                          \
    vd1.x = pack_bf(VR[0].y, VR[1].y);                          \
    vd1.y = pack_bf(VR[2].y, VR[3].y);                          \
    *(uint2*)&KLS[kb0] = kd0;                                   \
    *(uint2*)&KLS[kb1] = kd1;                                   \
    *(uint2*)&VLS[vb0] = vd0;                                   \
    *(uint2*)&VLS[vb1] = vd1;                                   \
  } while (0)

#define FRAGS_MFMA(KLS, VLS)                                                       \
  do {                                                                             \
    bf16x8 af[4], bfr[2];                                                          \
    _Pragma("unroll") for (int fr = 0; fr < 4; ++fr) {                             \
      int d = wr * 64 + fr * 16 + lr;                                              \
      af[fr] = *(const bf16x8*)&KLS[d * SP + ((4 * lg) ^ (4 * ((d >> 3) & 3)))];   \
    }                                                                              \
    _Pragma("unroll") for (int fc = 0; fc < 2; ++fc) {                             \
      int v = wc * 32 + fc * 16 + lr;                                              \
      bfr[fc] = *(const bf16x8*)&VLS[v * SP + ((4 * lg) ^ (4 * ((v >> 3) & 3)))];  \
    }                                                                              \
    _Pragma("unroll") for (int fr = 0; fr < 4; ++fr)                               \
      _Pragma("unroll") for (int fc = 0; fc < 2; ++fc)                             \
        acc[fr][fc] =                                                              \
            __builtin_amdgcn_mfma_f32_16x16x32_bf16(af[fr], bfr[fc], acc[fr][fc], 0, 0, 0); \
    if (wc == 0) {                                                                 \
      _Pragma("unroll") for (int fr = 0; fr < 4; ++fr)                             \
        ak[fr] = __builtin_amdgcn_mfma_f32_16x16x32_bf16(af[fr], ones, ak[fr], 0, 0, 0); \
    }                                                                              \
  } while (0)

  float2 krP[4], vrP[4], krQ[4], vrQ[4];
  ISSUE(krP, vrP, 0);
  ISSUE(krQ, vrQ, 1);

  for (int t = 0; t < steps; t += 2) {
    // even substep: P -> A
    STAGE(klsA, vlsA, krP, vrP);
    __syncthreads();
    if (t + 2 < steps) ISSUE(krP, vrP, t + 2);
    FRAGS_MFMA(klsA, vlsA);
    // odd substep: Q -> B
    STAGE(klsB, vlsB, krQ, vrQ);
    __syncthreads();
    if (t + 3 < steps) ISSUE(krQ, vrQ, t + 3);
    FRAGS_MFMA(klsB, vlsB);
  }
#undef ISSUE
#undef STAGE
#undef FRAGS_MFMA

  // C/D: col(v)=lane&15, row(d)=(lane>>4)*4+j. fp32 partial, write-once.
  float* dst = kvp + ((size_t)chunk * 32 + nh) * 16384;
#pragma unroll
  for (int fr = 0; fr < 4; ++fr)
#pragma unroll
    for (int fc = 0; fc < 2; ++fc) {
      int d0 = wr * 64 + fr * 16 + lg * 4;
      int v  = wc * 32 + fc * 16 + lr;
      *(float4*)(dst + (size_t)v * 128 + d0) =
          make_float4(acc[fr][fc][0], acc[fr][fc][1], acc[fr][fc][2], acc[fr][fc][3]);
    }
  if (wc == 0 && lr == 0) {
    float* ks = kspart + ((size_t)chunk * 32 + nh) * 128;
#pragma unroll
    for (int fr = 0; fr < 4; ++fr)
      *(float4*)(ks + wr * 64 + fr * 16 + lg * 4) =
          make_float4(ak[fr][0], ak[fr][1], ak[fr][2], ak[fr][3]);
  }
}

// ---------------- Phase 1c: merge partials ----------------
__global__ __launch_bounds__(256) void kv_merge(const float* __restrict__ kvp,
                                                const float* __restrict__ kspart,
                                                ushort_t* __restrict__ kvb,
                                                float* __restrict__ ksumg,
                                                int CH) {
  const int nh = blockIdx.x, q = blockIdx.y, tid = threadIdx.x;
  const size_t off = (size_t)nh * 16384 + q * 4096;
#pragma unroll
  for (int i = 0; i < 4; ++i) {
    size_t idx = off + (size_t)(i * 256 + tid) * 4;
    f32x4 s = {};
    for (int c = 0; c < CH; ++c)
      s += *(const f32x4*)(kvp + (size_t)c * 524288 + idx);
    *(uint2*)(kvb + idx) = make_uint2(pack_bf(s[0], s[1]), pack_bf(s[2], s[3]));
  }
  if (q == 0 && tid < 128) {
    float s = 0.f;
    for (int c = 0; c < CH; ++c) s += kspart[((size_t)c * 32 + nh) * 128 + tid];
    ksumg[nh * 128 + tid] = s;
  }
}

// ---------------- Phase 2: LDS-staged Q + direct-global B ----------------
__global__ __launch_bounds__(256, 4) void attn_out(const float* __restrict__ q,
                                                   const ushort_t* __restrict__ kvb,
                                                   const float* __restrict__ ksumg,
                                                   const float* __restrict__ thrp,
                                                   float* __restrict__ out) {
  __shared__ __align__(16) uint32_t As[128 * 17 * 4];  // 34.8KB
  __shared__ float zrow[128];

  const int tid = threadIdx.x;
  const int mc = blockIdx.x, nh = blockIdx.y;
  const int n = nh >> 3, h = nh & 7;
  const size_t qoff = ((size_t)(n * LSEQ + mc * 128)) * NHD + h * 128;
  const float thr = thrp[0];

  const int c4 = tid & 31;
  const float4 kk = *(const float4*)(ksumg + nh * 128 + c4 * 4);

  // ---- stage Qf -> As (bf16) + fp32 score on the fly ----
#pragma unroll
  for (int it = 0; it < 16; ++it) {
    int rr = it * 8 + (tid >> 5);
    float4 qv = *(const float4*)(q + qoff + (size_t)rr * NHD + c4 * 4);
    float f0 = featmap(qv.x), f1 = featmap(qv.y), f2 = featmap(qv.z), f3 = featmap(qv.w);
    uint32_t* dst = &As[(rr * 17 + (c4 >> 1)) * 4 + (c4 & 1) * 2];
    dst[0] = pack_bf(f0, f1);
    dst[1] = pack_bf(f2, f3);
    float p = f0 * kk.x + f1 * kk.y + f2 * kk.z + f3 * kk.w;
    p += __shfl_xor(p, 1);  p += __shfl_xor(p, 2);  p += __shfl_xor(p, 4);
    p += __shfl_xor(p, 8);  p += __shfl_xor(p, 16);
    if (c4 == 0) {
      float sp = p > thr ? p : 0.f;
      zrow[rr] = 1.f / (sp + 1e-6f);
    }
  }
  __syncthreads();

  // ---- MFMA: A from LDS, B direct from kvb (L2-hot 32KB) ----
  const int lane = tid & 63;
  const int w = tid >> 6;
  const int lr = lane & 15, lg = lane >> 4;
  const ushort_t* kvp = kvb + (size_t)nh * 16384;   // [v][d] bf16

  f32x4 acc0[8] = {};
  f32x4 acc1[8] = {};
#pragma unroll
  for (int ks = 0; ks < 4; ++ks) {
    const int c8 = ks * 4 + lg;
    const int dof = ks * 32 + lg * 8;
    const int r0 = w * 32 + lr;
    bf16x8 a0 = *(const bf16x8*)&As[(r0 * 17 + c8) * 4];
    bf16x8 a1 = *(const bf16x8*)&As[((r0 + 16) * 17 + c8) * 4];
#pragma unroll
    for (int ct = 0; ct < 8; ++ct) {
      bf16x8 bb = *(const bf16x8*)(kvp + (size_t)((ct * 16 + lr) * 128) + dof);
      acc0[ct] = __builtin_amdgcn_mfma_f32_16x16x32_bf16(a0, bb, acc0[ct], 0, 0, 0);
      acc1[ct] = __builtin_amdgcn_mfma_f32_16x16x32_bf16(a1, bb, acc1[ct], 0, 0, 0);
    }
  }

  float z0[4], z1[4];
#pragma unroll
  for (int j = 0; j < 4; ++j) {
    z0[j] = zrow[w * 32 + lg * 4 + j];
    z1[j] = zrow[w * 32 + 16 + lg * 4 + j];
  }
  float* op = out + qoff;
#pragma unroll
  for (int ct = 0; ct < 8; ++ct)
#pragma unroll
    for (int jj = 0; jj < 4; ++jj) {
      int row = w * 32 + lg * 4 + jj;   // C/D: col=lane&15, row=(lane>>4)*4+jj
      op[(size_t)row * NHD + ct * 16 + lr]        = acc0[ct][jj] * z0[jj];
      op[(size_t)(row + 16) * NHD + ct * 16 + lr] = acc1[ct][jj] * z1[jj];
    }
}

extern "C" void kernel_launch(void* const* d_in, const int* in_sizes, int n_in,
                              void* d_out, int out_size, void* d_ws, size_t ws_size,
                              hipStream_t stream) {
  const float* queries   = (const float*)d_in[0];
  const float* keys      = (const float*)d_in[1];
  const float* values    = (const float*)d_in[2];
  const float* threshold = (const float*)d_in[3];
  float* out = (float*)d_out;

  // ws: kvp CH*2MB fp32 | kspart CH*16KB | kvb 1MB | ksumg 16KB (CH=16 ~34.9MB)
  int CH = 16;
  while (CH > 1 &&
         (size_t)CH * (524288 + 32 * 128) * 4 + (size_t)32 * 16384 * 2 + 32 * 128 * 4 > ws_size)
    CH >>= 1;
  float* kvp     = (float*)d_ws;
  float* kspart  = kvp + (size_t)CH * 524288;
  ushort_t* kvb  = (ushort_t*)(kspart + (size_t)CH * 32 * 128);
  float* ksumg   = (float*)(kvb + (size_t)32 * 16384);

  kv_direct<<<dim3(CH, 8, 4), 512, 0, stream>>>(keys, values, kvp, kspart);
  kv_merge<<<dim3(32, 4), 256, 0, stream>>>(kvp, kspart, kvb, ksumg, CH);
  attn_out<<<dim3(64, 32), 256, 0, stream>>>(queries, kvb, ksumg, threshold, out);
}

// Round 17
// 172.464 us; speedup vs baseline: 1.3049x; 1.0095x over previous
//
#include <hip/hip_runtime.h>
#include <stdint.h>

// DynamicSparseLinearAttention on MI355X.
// N=4, L=8192, H=8, D=V=128. Layout [n][l][h][d], row stride H*D = 1024 floats.
//
// Lessons: (R4) atomics write through L2 -> never. (R5) small grids starve the
// chip. (R6) strided per-lane loads w/o staging thrash L2. (R8) scalar LDS
// transpose reads -> stage transposed+bf16-packed, b128 frag reads. (R9-R15)
// 7 structural mechanisms (load width, occupancy, conflicts, prefetch depth,
// barrier flavor, burst shape [R14's burst was VGPR-serialized: VGPR_Count=128
// can't hold 32 float4 -> never a real burst], channel stagger) all null:
// phase-1 pinned at ~97-104us (~3.1 TB/s demand) vs attn_out at the session
// pattern ceiling (~4.5 TB/s). R16 = exact R10 best config + T5 s_setprio
// around MFMA clusters (the one catalog technique whose regime -- phase-split
// multi-wave schedule -- matches and was never tested; m218b/m224: +21-39%
// on phase-split GEMM, m191: +4-7% attn).
//
// 3 launches:
//  kv_direct: fused retile+GEMM. Grid (CH=16,8,4)=512 blocks x 512 thr (8 waves
//             = 2 wr(d64) x 4 wc(v32)). Pipeline: regs P/Q hold steps t+2/t+3;
//             LDS buffers A/B alternate; one __syncthreads per substep. LDS
//             [d][s2^f(d)], SP=20; b64 writes, b128 frag reads. fp32 partials,
//             write-once, no atomics. Ksum via ones-MFMA on wc==0 waves.
//             setprio(1) around the MFMA cluster (T5).
//  kv_merge:  sum CH partials -> kvb bf16 [nh][v][d] + ksumg.
//  attn_out:  Q staged to LDS bf16 (row*17 padded chunks), score during staging
//             (fp32 + shfl_xor), B-frags direct from L2-hot kvb. One barrier.
//             setprio(1) around the MFMA loop (T5, m191 regime).

#define LSEQ 8192
#define NHD  1024   // H*D
#define SP   20     // LDS dwords per d-row: 16 s-pair slots + 4 pad

typedef __attribute__((ext_vector_type(4))) float f32x4;
typedef __attribute__((ext_vector_type(8))) short bf16x8;
typedef unsigned short ushort_t;

static __device__ __forceinline__ unsigned short f2bf(float x) {
  union { float f; uint32_t u; } v; v.f = x;
  uint32_t r = v.u + 0x7FFFu + ((v.u >> 16) & 1u);  // RNE
  return (unsigned short)(r >> 16);
}
static __device__ __forceinline__ uint32_t pack_bf(float a, float b) {
  return (uint32_t)f2bf(a) | ((uint32_t)f2bf(b) << 16);
}
static __device__ __forceinline__ float featmap(float x) {
  // elu(x)+1 = x+1 (x>0) else exp(x)
  return x > 0.f ? x + 1.f : __expf(x);
}

// ---------------- Phase 1: fused retile + KV GEMM, 2-deep pipeline ----------
// Grid (CH, 8 h, 4 n), 512 thr = 8 waves = 2 wr(d64) x 4 wc(v32).
__global__ __launch_bounds__(512, 4) void kv_direct(const float* __restrict__ keys,
                                                    const float* __restrict__ values,
                                                    float* __restrict__ kvp,
                                                    float* __restrict__ kspart) {
  __shared__ uint32_t klsA[128 * SP];
  __shared__ uint32_t vlsA[128 * SP];
  __shared__ uint32_t klsB[128 * SP];
  __shared__ uint32_t vlsB[128 * SP];
  const int tid = threadIdx.x;
  const int chunk = blockIdx.x, CH = gridDim.x;
  const int h = blockIdx.y, n = blockIdx.z, nh = n * 8 + h;
  const int lane = tid & 63, w = tid >> 6;
  const int wr = w >> 2, wc = w & 3;
  const int lr = lane & 15, lg = lane >> 4;
  const int sPer = LSEQ / CH;        // 512 at CH=16
  const int steps = sPer / 32;       // 16 at CH=16 (always even)

  const size_t gb = ((size_t)n * LSEQ + (size_t)chunk * sPer) * NHD + h * 128;
  const float* gk = keys + gb;
  const float* gv = values + gb;

  // staging role: wave w owns s = 4w..4w+3; lane a owns d-pair (2a, 2a+1)
  const int a = lane;
  const int fsw = 4 * ((a >> 2) & 3);          // = 4*((d>>3)&3) for d=2a,2a+1
  const int wslot = (2 * w) ^ fsw;
  const int wbase0 = (2 * a) * SP + wslot;
  const int wbase1 = (2 * a + 1) * SP + wslot;

  f32x4 acc[4][2] = {};
  f32x4 ak[4] = {};
  bf16x8 ones;
  { uint32_t* u = (uint32_t*)&ones; u[0] = u[1] = u[2] = u[3] = 0x3F803F80u; }

#define ISSUE(KR, VR, T)                                        \
  do {                                                          \
    _Pragma("unroll") for (int j = 0; j < 4; ++j) {             \
      size_t off = (size_t)((T) * 32 + 4 * w + j) * NHD + 2 * a;\
      KR[j] = *(const float2*)(gk + off);                       \
      VR[j] = *(const float2*)(gv + off);                       \
    }                                                           \
  } while (0)

#define STAGE(KLS, VLS, KR, VR)                                 \
  do {                                                          \
    uint2 kd0, kd1, vd0, vd1;                                   \
    kd0.x = pack_bf(featmap(KR[0].x), featmap(KR[1].x));        \
    kd0.y = pack_bf(featmap(KR[2].x), featmap(KR[3].x));        \
    kd1.x = pack_bf(featmap(KR[0].y), featmap(KR[1].y));        \
    kd1.y = pack_bf(featmap(KR[2].y), featmap(KR[3].y));        \
    vd0.x = pack_bf(VR[0].x, VR[1].x);                          \
    vd0.y = pack_bf(VR[2].x, VR[3].x);                          \
    vd1.x = pack_bf(VR[0].y, VR[1].y);                          \
    vd1.y = pack_bf(VR[2].y, VR[3].y);                          \
    *(uint2*)&KLS[wbase0] = kd0;                                \
    *(uint2*)&KLS[wbase1] = kd1;                                \
    *(uint2*)&VLS[wbase0] = vd0;                                \
    *(uint2*)&VLS[wbase1] = vd1;                                \
  } while (0)

#define FRAGS_MFMA(KLS, VLS)                                                       \
  do {                                                                             \
    bf16x8 af[4], bfr[2];                                                          \
    _Pragma("unroll") for (int fr = 0; fr < 4; ++fr) {                             \
      int d = wr * 64 + fr * 16 + lr;                                              \
      af[fr] = *(const bf16x8*)&KLS[d * SP + ((4 * lg) ^ (4 * ((d >> 3) & 3)))];   \
    }                                                                              \
    _Pragma("unroll") for (int fc = 0; fc < 2; ++fc) {                             \
      int v = wc * 32 + fc * 16 + lr;                                              \
      bfr[fc] = *(const bf16x8*)&VLS[v * SP + ((4 * lg) ^ (4 * ((v >> 3) & 3)))];  \
    }                                                                              \
    __builtin_amdgcn_s_setprio(1);                                                 \
    _Pragma("unroll") for (int fr = 0; fr < 4; ++fr)                               \
      _Pragma("unroll") for (int fc = 0; fc < 2; ++fc)                             \
        acc[fr][fc] =                                                              \
            __builtin_amdgcn_mfma_f32_16x16x32_bf16(af[fr], bfr[fc], acc[fr][fc], 0, 0, 0); \
    if (wc == 0) {                                                                 \
      _Pragma("unroll") for (int fr = 0; fr < 4; ++fr)                             \
        ak[fr] = __builtin_amdgcn_mfma_f32_16x16x32_bf16(af[fr], ones, ak[fr], 0, 0, 0); \
    }                                                                              \
    __builtin_amdgcn_s_setprio(0);                                                 \
  } while (0)

  float2 krP[4], vrP[4], krQ[4], vrQ[4];
  ISSUE(krP, vrP, 0);
  ISSUE(krQ, vrQ, 1);

  for (int t = 0; t < steps; t += 2) {
    // even substep: P -> A
    STAGE(klsA, vlsA, krP, vrP);
    __syncthreads();
    if (t + 2 < steps) ISSUE(krP, vrP, t + 2);
    FRAGS_MFMA(klsA, vlsA);
    // odd substep: Q -> B
    STAGE(klsB, vlsB, krQ, vrQ);
    __syncthreads();
    if (t + 3 < steps) ISSUE(krQ, vrQ, t + 3);
    FRAGS_MFMA(klsB, vlsB);
  }
#undef ISSUE
#undef STAGE
#undef FRAGS_MFMA

  // C/D: col(v)=lane&15, row(d)=(lane>>4)*4+j. fp32 partial, write-once.
  float* dst = kvp + ((size_t)chunk * 32 + nh) * 16384;
#pragma unroll
  for (int fr = 0; fr < 4; ++fr)
#pragma unroll
    for (int fc = 0; fc < 2; ++fc) {
      int d0 = wr * 64 + fr * 16 + lg * 4;
      int v  = wc * 32 + fc * 16 + lr;
      *(float4*)(dst + (size_t)v * 128 + d0) =
          make_float4(acc[fr][fc][0], acc[fr][fc][1], acc[fr][fc][2], acc[fr][fc][3]);
    }
  if (wc == 0 && lr == 0) {
    float* ks = kspart + ((size_t)chunk * 32 + nh) * 128;
#pragma unroll
    for (int fr = 0; fr < 4; ++fr)
      *(float4*)(ks + wr * 64 + fr * 16 + lg * 4) =
          make_float4(ak[fr][0], ak[fr][1], ak[fr][2], ak[fr][3]);
  }
}

// ---------------- Phase 1c: merge partials ----------------
__global__ __launch_bounds__(256) void kv_merge(const float* __restrict__ kvp,
                                                const float* __restrict__ kspart,
                                                ushort_t* __restrict__ kvb,
                                                float* __restrict__ ksumg,
                                                int CH) {
  const int nh = blockIdx.x, q = blockIdx.y, tid = threadIdx.x;
  const size_t off = (size_t)nh * 16384 + q * 4096;
#pragma unroll
  for (int i = 0; i < 4; ++i) {
    size_t idx = off + (size_t)(i * 256 + tid) * 4;
    f32x4 s = {};
    for (int c = 0; c < CH; ++c)
      s += *(const f32x4*)(kvp + (size_t)c * 524288 + idx);
    *(uint2*)(kvb + idx) = make_uint2(pack_bf(s[0], s[1]), pack_bf(s[2], s[3]));
  }
  if (q == 0 && tid < 128) {
    float s = 0.f;
    for (int c = 0; c < CH; ++c) s += kspart[((size_t)c * 32 + nh) * 128 + tid];
    ksumg[nh * 128 + tid] = s;
  }
}

// ---------------- Phase 2: LDS-staged Q + direct-global B ----------------
__global__ __launch_bounds__(256, 4) void attn_out(const float* __restrict__ q,
                                                   const ushort_t* __restrict__ kvb,
                                                   const float* __restrict__ ksumg,
                                                   const float* __restrict__ thrp,
                                                   float* __restrict__ out) {
  __shared__ __align__(16) uint32_t As[128 * 17 * 4];  // 34.8KB
  __shared__ float zrow[128];

  const int tid = threadIdx.x;
  const int mc = blockIdx.x, nh = blockIdx.y;
  const int n = nh >> 3, h = nh & 7;
  const size_t qoff = ((size_t)(n * LSEQ + mc * 128)) * NHD + h * 128;
  const float thr = thrp[0];

  const int c4 = tid & 31;
  const float4 kk = *(const float4*)(ksumg + nh * 128 + c4 * 4);

  // ---- stage Qf -> As (bf16) + fp32 score on the fly ----
#pragma unroll
  for (int it = 0; it < 16; ++it) {
    int rr = it * 8 + (tid >> 5);
    float4 qv = *(const float4*)(q + qoff + (size_t)rr * NHD + c4 * 4);
    float f0 = featmap(qv.x), f1 = featmap(qv.y), f2 = featmap(qv.z), f3 = featmap(qv.w);
    uint32_t* dst = &As[(rr * 17 + (c4 >> 1)) * 4 + (c4 & 1) * 2];
    dst[0] = pack_bf(f0, f1);
    dst[1] = pack_bf(f2, f3);
    float p = f0 * kk.x + f1 * kk.y + f2 * kk.z + f3 * kk.w;
    p += __shfl_xor(p, 1);  p += __shfl_xor(p, 2);  p += __shfl_xor(p, 4);
    p += __shfl_xor(p, 8);  p += __shfl_xor(p, 16);
    if (c4 == 0) {
      float sp = p > thr ? p : 0.f;
      zrow[rr] = 1.f / (sp + 1e-6f);
    }
  }
  __syncthreads();

  // ---- MFMA: A from LDS, B direct from kvb (L2-hot 32KB) ----
  const int lane = tid & 63;
  const int w = tid >> 6;
  const int lr = lane & 15, lg = lane >> 4;
  const ushort_t* kvp = kvb + (size_t)nh * 16384;   // [v][d] bf16

  f32x4 acc0[8] = {};
  f32x4 acc1[8] = {};
  __builtin_amdgcn_s_setprio(1);
#pragma unroll
  for (int ks = 0; ks < 4; ++ks) {
    const int c8 = ks * 4 + lg;
    const int dof = ks * 32 + lg * 8;
    const int r0 = w * 32 + lr;
    bf16x8 a0 = *(const bf16x8*)&As[(r0 * 17 + c8) * 4];
    bf16x8 a1 = *(const bf16x8*)&As[((r0 + 16) * 17 + c8) * 4];
#pragma unroll
    for (int ct = 0; ct < 8; ++ct) {
      bf16x8 bb = *(const bf16x8*)(kvp + (size_t)((ct * 16 + lr) * 128) + dof);
      acc0[ct] = __builtin_amdgcn_mfma_f32_16x16x32_bf16(a0, bb, acc0[ct], 0, 0, 0);
      acc1[ct] = __builtin_amdgcn_mfma_f32_16x16x32_bf16(a1, bb, acc1[ct], 0, 0, 0);
    }
  }
  __builtin_amdgcn_s_setprio(0);

  float z0[4], z1[4];
#pragma unroll
  for (int j = 0; j < 4; ++j) {
    z0[j] = zrow[w * 32 + lg * 4 + j];
    z1[j] = zrow[w * 32 + 16 + lg * 4 + j];
  }
  float* op = out + qoff;
#pragma unroll
  for (int ct = 0; ct < 8; ++ct)
#pragma unroll
    for (int jj = 0; jj < 4; ++jj) {
      int row = w * 32 + lg * 4 + jj;   // C/D: col=lane&15, row=(lane>>4)*4+jj
      op[(size_t)row * NHD + ct * 16 + lr]        = acc0[ct][jj] * z0[jj];
      op[(size_t)(row + 16) * NHD + ct * 16 + lr] = acc1[ct][jj] * z1[jj];
    }
}

extern "C" void kernel_launch(void* const* d_in, const int* in_sizes, int n_in,
                              void* d_out, int out_size, void* d_ws, size_t ws_size,
                              hipStream_t stream) {
  const float* queries   = (const float*)d_in[0];
  const float* keys      = (const float*)d_in[1];
  const float* values    = (const float*)d_in[2];
  const float* threshold = (const float*)d_in[3];
  float* out = (float*)d_out;

  // ws: kvp CH*2MB fp32 | kspart CH*16KB | kvb 1MB | ksumg 16KB (CH=16 ~34.9MB)
  int CH = 16;
  while (CH > 1 &&
         (size_t)CH * (524288 + 32 * 128) * 4 + (size_t)32 * 16384 * 2 + 32 * 128 * 4 > ws_size)
    CH >>= 1;
  float* kvp     = (float*)d_ws;
  float* kspart  = kvp + (size_t)CH * 524288;
  ushort_t* kvb  = (ushort_t*)(kspart + (size_t)CH * 32 * 128);
  float* ksumg   = (float*)(kvb + (size_t)32 * 16384);

  kv_direct<<<dim3(CH, 8, 4), 512, 0, stream>>>(keys, values, kvp, kspart);
  kv_merge<<<dim3(32, 4), 256, 0, stream>>>(kvp, kspart, kvb, ksumg, CH);
  attn_out<<<dim3(64, 32), 256, 0, stream>>>(queries, kvb, ksumg, threshold, out);
}